// Round 1
// baseline (6219.103 us; speedup 1.0000x reference)
//
#include <hip/hip_runtime.h>

// LiquidNeuralNetwork: B=512, S=1024, IN=16, HID=64, OUT=1, N_SUB=4 (RK4).
// Strategy: one wave (64 lanes) per batch element; lane i owns hidden unit i.
// W_hh row lives in 64 VGPRs; tanh(h) broadcast via a per-wave 256B LDS buffer
// (intra-wave only -> no barriers needed; LDS pipe is in-order per wave).
// inp = (x W_in^T + b_in) W_ih^T folded to x @ W_comb^T + const (W_comb = W_ih W_in).

constexpr int HID  = 64;
constexpr int INF  = 16;
constexpr int SLEN = 1024;
constexpr int NSUB = 4;

__device__ __forceinline__ float fast_tanh(float x) {
    float xc = fminf(fmaxf(x, -9.0f), 9.0f);
    float e2 = __expf(2.0f * xc);               // v_exp based
    return __fdividef(e2 - 1.0f, e2 + 1.0f);    // v_rcp based, ~1ulp
}

__global__ __launch_bounds__(64, 1) void lnn_scan_kernel(
    const float* __restrict__ x,
    const float* __restrict__ W_in,
    const float* __restrict__ b_in,
    const float* __restrict__ W_hh,
    const float* __restrict__ W_ih,
    const float* __restrict__ bias,
    const float* __restrict__ tau,
    const float* __restrict__ W_out,
    const float* __restrict__ b_out,
    float* __restrict__ out)
{
    const int lane = threadIdx.x;   // hidden index
    const int b    = blockIdx.x;    // batch index

    __shared__ float th_s[HID];     // one wave per block -> wave-private

    // --- one-time setup (amortized over 16384 evals) ---
    float w[HID];
    #pragma unroll
    for (int j = 0; j < HID; ++j) w[j] = W_hh[lane * HID + j];

    float Wc[INF];
    #pragma unroll
    for (int k = 0; k < INF; ++k) Wc[k] = 0.0f;
    float bcomb = 0.0f;
    for (int j = 0; j < HID; ++j) {
        float wij = W_ih[lane * HID + j];
        bcomb = fmaf(wij, b_in[j], bcomb);
        #pragma unroll
        for (int k = 0; k < INF; ++k) Wc[k] = fmaf(wij, W_in[j * INF + k], Wc[k]);
    }
    const float cbase = bcomb + bias[lane];
    const float rtau  = 1.0f / tau[lane];   // tau==1 -> exact
    const float wo    = W_out[lane];
    const float bo    = b_out[0];

    float c_step = 0.0f;

    // ode_f(y) = (matvec(tanh(y)) + c - y) * rtau
    auto odef = [&](float y) -> float {
        float th = fast_tanh(y);
        th_s[lane] = th;                       // intra-wave: no barrier needed
        float a0 = 0.f, a1 = 0.f, a2 = 0.f, a3 = 0.f;
        const float4* t4 = (const float4*)th_s;
        #pragma unroll
        for (int q = 0; q < HID / 4; ++q) {    // 16x ds_read_b128 + 64 FMA
            float4 t = t4[q];
            a0 = fmaf(w[4*q+0], t.x, a0);
            a1 = fmaf(w[4*q+1], t.y, a1);
            a2 = fmaf(w[4*q+2], t.z, a2);
            a3 = fmaf(w[4*q+3], t.w, a3);
        }
        return ((a0 + a1) + (a2 + a3) + c_step - y) * rtau;
    };

    float h = 0.0f;
    const float inv1023 = 1.0f / 1023.0f;      // linspace(0,1,1024) step
    float tprev = 0.0f;

    const float4* xrow = (const float4*)(x + (size_t)b * SLEN * INF);

    for (int s = 0; s < SLEN; ++s) {
        // dts = concat([t[0]], diff(t)); t[0]=0
        float tcur = (float)s * inv1023;
        float dt   = (s == 0) ? 0.0f : (tcur - tprev);
        tprev = tcur;
        float hsub = 0.25f * dt;               // dt / N_SUB

        // c = inp + bias = x_t @ W_comb^T + cbase  (wave-uniform x loads)
        float4 x0 = xrow[s*4+0], x1 = xrow[s*4+1], x2 = xrow[s*4+2], x3 = xrow[s*4+3];
        float c = cbase;
        c = fmaf(x0.x, Wc[ 0], c); c = fmaf(x0.y, Wc[ 1], c);
        c = fmaf(x0.z, Wc[ 2], c); c = fmaf(x0.w, Wc[ 3], c);
        c = fmaf(x1.x, Wc[ 4], c); c = fmaf(x1.y, Wc[ 5], c);
        c = fmaf(x1.z, Wc[ 6], c); c = fmaf(x1.w, Wc[ 7], c);
        c = fmaf(x2.x, Wc[ 8], c); c = fmaf(x2.y, Wc[ 9], c);
        c = fmaf(x2.z, Wc[10], c); c = fmaf(x2.w, Wc[11], c);
        c = fmaf(x3.x, Wc[12], c); c = fmaf(x3.y, Wc[13], c);
        c = fmaf(x3.z, Wc[14], c); c = fmaf(x3.w, Wc[15], c);
        c_step = c;

        #pragma unroll
        for (int sub = 0; sub < NSUB; ++sub) {
            float k1 = odef(h);
            float k2 = odef(fmaf(0.5f * hsub, k1, h));
            float k3 = odef(fmaf(0.5f * hsub, k2, h));
            float k4 = odef(fmaf(hsub, k3, h));
            h = fmaf(hsub * (1.0f / 6.0f), fmaf(2.0f, k2 + k3, k1 + k4), h);
        }

        // out[b,s,0] = tanh(h) . W_out + b_out  (64-lane butterfly reduce)
        float val = fast_tanh(h) * wo;
        #pragma unroll
        for (int m = 32; m > 0; m >>= 1) val += __shfl_xor(val, m, 64);
        if (lane == 0) out[(size_t)b * SLEN + s] = val + bo;
    }
}

extern "C" void kernel_launch(void* const* d_in, const int* in_sizes, int n_in,
                              void* d_out, int out_size, void* d_ws, size_t ws_size,
                              hipStream_t stream) {
    const float* x     = (const float*)d_in[0];
    const float* W_in  = (const float*)d_in[1];
    const float* b_in  = (const float*)d_in[2];
    const float* W_hh  = (const float*)d_in[3];
    const float* W_ih  = (const float*)d_in[4];
    const float* bias  = (const float*)d_in[5];
    const float* tau   = (const float*)d_in[6];
    const float* W_out = (const float*)d_in[7];
    const float* b_out = (const float*)d_in[8];
    float* out = (float*)d_out;

    const int B = 512;
    lnn_scan_kernel<<<B, 64, 0, stream>>>(x, W_in, b_in, W_hh, W_ih, bias,
                                          tau, W_out, b_out, out);
}

// Round 2
// 5871.987 us; speedup vs baseline: 1.0591x; 1.0591x over previous
//
#include <hip/hip_runtime.h>

// LiquidNeuralNetwork: B=512, S=1024, IN=16, HID=64, OUT=1, N_SUB=4 (RK4).
// One wave per batch element; lane i owns hidden unit i. W_hh row in VGPRs;
// tanh(h) broadcast via wave-private 256B LDS buffer (no barriers: DS pipe is
// in-order per wave). Output dot fused into the first eval of the NEXT step
// (same broadcast vector) -> no shuffle butterfly. dt is constant (linspace).

constexpr int HID  = 64;
constexpr int INF  = 16;
constexpr int SLEN = 1024;

__device__ __forceinline__ float fast_tanh(float x) {
    // tanh(x) = 1 - 2/(e^{2x}+1); exact limits at +/-inf, no clamp needed.
    float e = __builtin_amdgcn_exp2f(x * 2.8853900817779268f); // 2*log2(e)
    float r = __builtin_amdgcn_rcpf(e + 1.0f);
    return fmaf(-2.0f, r, 1.0f);
}

__global__ __launch_bounds__(64, 1) void lnn_scan_kernel(
    const float* __restrict__ x,
    const float* __restrict__ W_in,
    const float* __restrict__ b_in,
    const float* __restrict__ W_hh,
    const float* __restrict__ W_ih,
    const float* __restrict__ bias,
    const float* __restrict__ tau,
    const float* __restrict__ W_out,
    const float* __restrict__ b_out,
    float* __restrict__ out)
{
    const int lane = threadIdx.x;   // hidden index
    const int b    = blockIdx.x;    // batch index

    __shared__ float th_s[HID];     // one wave per block -> wave-private

    // --- one-time setup (amortized over 16384 evals) ---
    float w[HID];                   // my W_hh row
    {
        const float4* w4 = (const float4*)(W_hh + lane * HID);
        #pragma unroll
        for (int q = 0; q < HID / 4; ++q) {
            float4 v = w4[q];
            w[4*q+0] = v.x; w[4*q+1] = v.y; w[4*q+2] = v.z; w[4*q+3] = v.w;
        }
    }
    float wov[HID];                 // full W_out row, replicated per lane
    {
        const float4* o4 = (const float4*)(W_out);
        #pragma unroll
        for (int q = 0; q < HID / 4; ++q) {
            float4 v = o4[q];
            wov[4*q+0] = v.x; wov[4*q+1] = v.y; wov[4*q+2] = v.z; wov[4*q+3] = v.w;
        }
    }

    float Wc[INF];                  // W_ih @ W_in row for my unit
    #pragma unroll
    for (int k = 0; k < INF; ++k) Wc[k] = 0.0f;
    float bcomb = 0.0f;
    for (int j = 0; j < HID; ++j) {
        float wij = W_ih[lane * HID + j];
        bcomb = fmaf(wij, b_in[j], bcomb);
        #pragma unroll
        for (int k = 0; k < INF; ++k) Wc[k] = fmaf(wij, W_in[j * INF + k], Wc[k]);
    }
    const float cbase = bcomb + bias[lane];
    const float rtau  = 1.0f / tau[lane];
    const float bo    = b_out[0];

    float c_step = 0.0f;

    // ode_f(y) = (matvec(tanh(y)) + c - y) * rtau
    auto odef = [&](float y) -> float {
        float th = fast_tanh(y);
        th_s[lane] = th;                       // intra-wave: no barrier
        float a0 = 0.f, a1 = 0.f, a2 = 0.f, a3 = 0.f;
        const float4* t4 = (const float4*)th_s;
        #pragma unroll
        for (int q = 0; q < HID / 4; ++q) {
            float4 t = t4[q];
            a0 = fmaf(w[4*q+0], t.x, a0);
            a1 = fmaf(w[4*q+1], t.y, a1);
            a2 = fmaf(w[4*q+2], t.z, a2);
            a3 = fmaf(w[4*q+3], t.w, a3);
        }
        return ((a0 + a1) + (a2 + a3) + c_step - y) * rtau;
    };

    // Same, but also produces os = sum_j wov[j]*tanh(y)_j (previous step's out)
    auto odef_out = [&](float y, float& os) -> float {
        float th = fast_tanh(y);
        th_s[lane] = th;
        float a0 = 0.f, a1 = 0.f, a2 = 0.f, a3 = 0.f;
        float o0 = 0.f, o1 = 0.f, o2 = 0.f, o3 = 0.f;
        const float4* t4 = (const float4*)th_s;
        #pragma unroll
        for (int q = 0; q < HID / 4; ++q) {
            float4 t = t4[q];
            a0 = fmaf(w[4*q+0], t.x, a0);
            a1 = fmaf(w[4*q+1], t.y, a1);
            a2 = fmaf(w[4*q+2], t.z, a2);
            a3 = fmaf(w[4*q+3], t.w, a3);
            o0 = fmaf(wov[4*q+0], t.x, o0);
            o1 = fmaf(wov[4*q+1], t.y, o1);
            o2 = fmaf(wov[4*q+2], t.z, o2);
            o3 = fmaf(wov[4*q+3], t.w, o3);
        }
        os = (o0 + o1) + (o2 + o3);
        return ((a0 + a1) + (a2 + a3) + c_step - y) * rtau;
    };

    float h = 0.0f;
    // dt = 1/1023 for all steps s>=1 (s=0 has dt=0 -> h unchanged, skipped)
    const float hsub = (1.0f / 1023.0f) * 0.25f;
    const float h6   = hsub * (1.0f / 6.0f);

    const float4* xrow = (const float4*)(x + (size_t)b * SLEN * INF);
    float* orow = out + (size_t)b * SLEN;

    // prefetch x for s=1
    float4 xp0 = xrow[4], xp1 = xrow[5], xp2 = xrow[6], xp3 = xrow[7];

    for (int s = 1; s < SLEN; ++s) {
        // c for this step from prefetched regs (4 parallel FMA chains)
        {
            float cA = fmaf(xp0.x, Wc[0], fmaf(xp0.y, Wc[1],
                       fmaf(xp0.z, Wc[2], fmaf(xp0.w, Wc[3], cbase))));
            float cB = fmaf(xp1.x, Wc[4], fmaf(xp1.y, Wc[5],
                       fmaf(xp1.z, Wc[6], xp1.w * Wc[7])));
            float cC = fmaf(xp2.x, Wc[8], fmaf(xp2.y, Wc[9],
                       fmaf(xp2.z, Wc[10], xp2.w * Wc[11])));
            float cD = fmaf(xp3.x, Wc[12], fmaf(xp3.y, Wc[13],
                       fmaf(xp3.z, Wc[14], xp3.w * Wc[15])));
            c_step = (cA + cB) + (cC + cD);
        }
        // prefetch next step's x (clamped index; hidden behind 16 evals)
        {
            int sn = (s < SLEN - 1) ? (s + 1) : (SLEN - 1);
            xp0 = xrow[sn*4+0]; xp1 = xrow[sn*4+1];
            xp2 = xrow[sn*4+2]; xp3 = xrow[sn*4+3];
        }

        // substep 0: first eval also yields previous step's output
        {
            float os;
            float k1 = odef_out(h, os);
            if (lane == 0) orow[s - 1] = os + bo;
            float k2 = odef(fmaf(0.5f * hsub, k1, h));
            float k3 = odef(fmaf(0.5f * hsub, k2, h));
            float k4 = odef(fmaf(hsub, k3, h));
            h = fmaf(h6, fmaf(2.0f, k2 + k3, k1 + k4), h);
        }
        #pragma unroll
        for (int sub = 1; sub < 4; ++sub) {
            float k1 = odef(h);
            float k2 = odef(fmaf(0.5f * hsub, k1, h));
            float k3 = odef(fmaf(0.5f * hsub, k2, h));
            float k4 = odef(fmaf(hsub, k3, h));
            h = fmaf(h6, fmaf(2.0f, k2 + k3, k1 + k4), h);
        }
    }

    // epilogue: out[1023] = wov . tanh(h_final) + bo
    {
        float th = fast_tanh(h);
        th_s[lane] = th;
        float o0 = 0.f, o1 = 0.f, o2 = 0.f, o3 = 0.f;
        const float4* t4 = (const float4*)th_s;
        #pragma unroll
        for (int q = 0; q < HID / 4; ++q) {
            float4 t = t4[q];
            o0 = fmaf(wov[4*q+0], t.x, o0);
            o1 = fmaf(wov[4*q+1], t.y, o1);
            o2 = fmaf(wov[4*q+2], t.z, o2);
            o3 = fmaf(wov[4*q+3], t.w, o3);
        }
        if (lane == 0) orow[SLEN - 1] = (o0 + o1) + (o2 + o3) + bo;
    }
}

extern "C" void kernel_launch(void* const* d_in, const int* in_sizes, int n_in,
                              void* d_out, int out_size, void* d_ws, size_t ws_size,
                              hipStream_t stream) {
    const float* x     = (const float*)d_in[0];
    const float* W_in  = (const float*)d_in[1];
    const float* b_in  = (const float*)d_in[2];
    const float* W_hh  = (const float*)d_in[3];
    const float* W_ih  = (const float*)d_in[4];
    const float* bias  = (const float*)d_in[5];
    const float* tau   = (const float*)d_in[6];
    const float* W_out = (const float*)d_in[7];
    const float* b_out = (const float*)d_in[8];
    float* out = (float*)d_out;

    lnn_scan_kernel<<<512, 64, 0, stream>>>(x, W_in, b_in, W_hh, W_ih, bias,
                                            tau, W_out, b_out, out);
}